// Round 9
// baseline (252.861 us; speedup 1.0000x reference)
//
#include <hip/hip_runtime.h>
#include <hip/hip_bf16.h>
#include <cstdint>
#include <cstddef>

#define B_  2
#define T_  4096
#define D_  768
#define H_  12
#define HD_ 64
#define M_  (B_*T_)   // 8192 rows

#define SCL 0.18033688f   // (1/sqrt(64)) * log2(e): folded into K projection

typedef __bf16 bf16x8 __attribute__((ext_vector_type(8)));
typedef float  f32x4  __attribute__((ext_vector_type(4)));
using bf16 = __hip_bfloat16;

__device__ inline float fexp2(float x) {
  float r; asm("v_exp_f32 %0, %1" : "=v"(r) : "v"(x)); return r;
}
__device__ inline uint32_t fu(float x) { union { float f; uint32_t u; } c; c.f = x; return c.u; }
__device__ inline uint32_t pktr(float a, float b) {   // truncated bf16 pair, 1 v_perm
  return __builtin_amdgcn_perm(fu(b), fu(a), 0x07060302);
}
#define GLD16(g, l) __builtin_amdgcn_global_load_lds( \
    (const __attribute__((address_space(1))) uint32_t*)(const void*)(g), \
    (__attribute__((address_space(3))) uint32_t*)(void*)(l), 16, 0, 0)

// ---------------- fp32 -> bf16 conversion (x + 4 weights, exact 1D grid) ---------
__global__ void cvt_all(const float* __restrict__ x,
                        const float* __restrict__ w0, const float* __restrict__ w1,
                        const float* __restrict__ w2, const float* __restrict__ w3,
                        bf16* __restrict__ xd,
                        bf16* __restrict__ d0, bf16* __restrict__ d1,
                        bf16* __restrict__ d2, bf16* __restrict__ d3) {
  int blk = blockIdx.x;
  const float* s; bf16* d; int i;
  if (blk < 6144) {                       // x: 6144*256 == M*D/4 exactly
    s = x; d = xd; i = blk * 256 + threadIdx.x;
  } else {                                // weights: 576*256 == D*D/4 exactly
    int q = blk - 6144, which = q / 576, rb = q % 576;
    switch (which) {
      case 0: s = w0; d = d0; break;
      case 1: s = w1; d = d1; break;
      case 2: s = w2; d = d2; break;
      default: s = w3; d = d3; break;
    }
    i = rb * 256 + threadIdx.x;
  }
  float4 v = ((const float4*)s)[i];
  union { bf16 o[4]; uint2 u; } pk;
  pk.o[0] = __float2bfloat16(v.x); pk.o[1] = __float2bfloat16(v.y);
  pk.o[2] = __float2bfloat16(v.z); pk.o[3] = __float2bfloat16(v.w);
  *(uint2*)(d + 4 * (size_t)i) = pk.u;
}

// ---------------- unified QKV GEMM (R8 structure + swizzle fix + K-phase stagger) -
// LDS swizzle: chunk c of row r at slot c ^ ((r>>1)&3)  -> frag ds_read_b128 is
// 2-way bank-aliased (free), vs 4-way with the old (r&3) xor.
// K-phase stagger: block processes k-slices in circular order starting at
// phase(blockIdx) -- decorrelates the per-CU blocks' barrier/load phases so
// inter-block MFMA/load overlap (m114) actually happens; sum is k-order-invariant.
__global__ __launch_bounds__(256) void gemm_qkv(const bf16* __restrict__ x,
                                                const bf16* __restrict__ W0,
                                                const bf16* __restrict__ W1,
                                                const bf16* __restrict__ W2,
                                                bf16* __restrict__ O0,
                                                bf16* __restrict__ O1,
                                                bf16* __restrict__ O2t) {
  __shared__ bf16 As[2][4096];
  __shared__ bf16 Bs[2][4096];
  const int flat = blockIdx.x;
  const int by = flat / 18;            // token tile (m)
  const int rr = flat % 18;
  const int z  = rr / 6;
  const int bx = rr % 6;               // feature tile (n)
  const bf16* Wz = (z == 0) ? W0 : ((z == 1) ? W1 : W2);
  const char* Ap; const char* Bp; int a0, b0;
  if (z == 2) { Ap = (const char*)x;  a0 = by * 128; Bp = (const char*)Wz; b0 = bx * 128; }
  else        { Ap = (const char*)Wz; a0 = bx * 128; Bp = (const char*)x;  b0 = by * 128; }
  const int t = threadIdx.x;
  const int w = t >> 6, lane = t & 63;
  const int wa = (w >> 1) * 64, wb = (w & 1) * 64;
  const int mi = lane & 15, qd = lane >> 4;

  int aoff[2], boff[2];
  #pragma unroll
  for (int i = 0; i < 2; ++i) {
    int L = i * 256 + t;
    int row = L >> 2, sl = L & 3, c = sl ^ ((row >> 1) & 3);
    aoff[i] = (a0 + row) * 1536 + c * 16;
    boff[i] = (b0 + row) * 1536 + c * 16;
  }
  const int fsw = (qd ^ ((mi >> 1) & 3)) * 8;

  f32x4 acc[4][4] = {};

  // circular K order: phase spread among the 18 blocks sharing an x panel
  int kb = ((flat * 5) % 24) * 64;     // byte offset of current k-slice
  #pragma unroll
  for (int i = 0; i < 2; ++i) {
    GLD16(Ap + aoff[i] + kb, &As[0][i * 2048 + w * 512]);
    GLD16(Bp + boff[i] + kb, &Bs[0][i * 2048 + w * 512]);
  }

  for (int kk = 0; kk < 24; ++kk) {
    __syncthreads();
    const int par = kk & 1;
    if (kk + 1 < 24) {
      int kbn = kb + 64; if (kbn == 1536) kbn = 0;
      kb = kbn;
      const int np = par ^ 1;
      #pragma unroll
      for (int i = 0; i < 2; ++i) {
        GLD16(Ap + aoff[i] + kbn, &As[np][i * 2048 + w * 512]);
        GLD16(Bp + boff[i] + kbn, &Bs[np][i * 2048 + w * 512]);
      }
    }
    bf16x8 af[4], bfr[4];
    #pragma unroll
    for (int at = 0; at < 4; ++at)
      af[at] = *(const bf16x8*)&As[par][(wa + at * 16 + mi) * 32 + fsw];
    #pragma unroll
    for (int bt = 0; bt < 4; ++bt)
      bfr[bt] = *(const bf16x8*)&Bs[par][(wb + bt * 16 + mi) * 32 + fsw];
    #pragma unroll
    for (int at = 0; at < 4; ++at)
      #pragma unroll
      for (int bt = 0; bt < 4; ++bt)
        acc[at][bt] = __builtin_amdgcn_mfma_f32_16x16x32_bf16(af[at], bfr[bt], acc[at][bt], 0, 0, 0);
  }

  // C layout: A-row (local) = qd*4+r, B-row = mi
  if (z == 2) {
    // A rows = tokens, B rows = features -> V^T [B][D][T], uint2 over 4 tokens
    #pragma unroll
    for (int at = 0; at < 4; ++at)
      #pragma unroll
      for (int bt = 0; bt < 4; ++bt) {
        int gr = a0 + wa + at * 16 + qd * 4;          // token
        int gc = b0 + wb + bt * 16 + mi;              // feature
        union { bf16 o[4]; uint2 u; } pk;
        #pragma unroll
        for (int r = 0; r < 4; ++r) pk.o[r] = __float2bfloat16(acc[at][bt][r]);
        int bb = gr >> 12, tt = gr & 4095;
        *(uint2*)(O2t + (size_t)bb * 768 * 4096 + (size_t)gc * 4096 + tt) = pk.u;
      }
  } else {
    // A rows = features, B rows = tokens -> packed uint2 per token
    const float scl = (z == 1) ? SCL : 1.0f;
    bf16* Ob = (z == 0) ? O0 : O1;
    #pragma unroll
    for (int at = 0; at < 4; ++at)
      #pragma unroll
      for (int bt = 0; bt < 4; ++bt) {
        int f0  = a0 + wa + at * 16 + qd * 4;
        int tkn = b0 + wb + bt * 16 + mi;
        union { bf16 o[4]; uint2 u; } pk;
        #pragma unroll
        for (int r = 0; r < 4; ++r) pk.o[r] = __float2bfloat16(acc[at][bt][r] * scl);
        *(uint2*)(Ob + (size_t)tkn * 768 + f0) = pk.u;
      }
  }
}

// ---------------- output projection (same fixes; float4 stores + bias) -----------
__global__ __launch_bounds__(256) void gemm_out(const bf16* __restrict__ ctx,
                                                const bf16* __restrict__ Wo,
                                                float* __restrict__ Cf,
                                                const float* __restrict__ bias) {
  __shared__ bf16 As[2][4096];
  __shared__ bf16 Bs[2][4096];
  const int flat = blockIdx.x;
  const int by = flat / 6, bx = flat % 6;
  const char* Ap = (const char*)Wo;  const int a0 = bx * 128;   // feature rows
  const char* Bp = (const char*)ctx; const int b0 = by * 128;   // token rows
  const int t = threadIdx.x;
  const int w = t >> 6, lane = t & 63;
  const int wa = (w >> 1) * 64, wb = (w & 1) * 64;
  const int mi = lane & 15, qd = lane >> 4;

  int aoff[2], boff[2];
  #pragma unroll
  for (int i = 0; i < 2; ++i) {
    int L = i * 256 + t;
    int row = L >> 2, sl = L & 3, c = sl ^ ((row >> 1) & 3);
    aoff[i] = (a0 + row) * 1536 + c * 16;
    boff[i] = (b0 + row) * 1536 + c * 16;
  }
  const int fsw = (qd ^ ((mi >> 1) & 3)) * 8;

  f32x4 acc[4][4] = {};

  int kb = ((flat * 5) % 24) * 64;
  #pragma unroll
  for (int i = 0; i < 2; ++i) {
    GLD16(Ap + aoff[i] + kb, &As[0][i * 2048 + w * 512]);
    GLD16(Bp + boff[i] + kb, &Bs[0][i * 2048 + w * 512]);
  }

  for (int kk = 0; kk < 24; ++kk) {
    __syncthreads();
    const int par = kk & 1;
    if (kk + 1 < 24) {
      int kbn = kb + 64; if (kbn == 1536) kbn = 0;
      kb = kbn;
      const int np = par ^ 1;
      #pragma unroll
      for (int i = 0; i < 2; ++i) {
        GLD16(Ap + aoff[i] + kbn, &As[np][i * 2048 + w * 512]);
        GLD16(Bp + boff[i] + kbn, &Bs[np][i * 2048 + w * 512]);
      }
    }
    bf16x8 af[4], bfr[4];
    #pragma unroll
    for (int at = 0; at < 4; ++at)
      af[at] = *(const bf16x8*)&As[par][(wa + at * 16 + mi) * 32 + fsw];
    #pragma unroll
    for (int bt = 0; bt < 4; ++bt)
      bfr[bt] = *(const bf16x8*)&Bs[par][(wb + bt * 16 + mi) * 32 + fsw];
    #pragma unroll
    for (int at = 0; at < 4; ++at)
      #pragma unroll
      for (int bt = 0; bt < 4; ++bt)
        acc[at][bt] = __builtin_amdgcn_mfma_f32_16x16x32_bf16(af[at], bfr[bt], acc[at][bt], 0, 0, 0);
  }

  #pragma unroll
  for (int at = 0; at < 4; ++at)
    #pragma unroll
    for (int bt = 0; bt < 4; ++bt) {
      int f0  = a0 + wa + at * 16 + qd * 4;
      int tkn = b0 + wb + bt * 16 + mi;
      float4 bv = *(const float4*)&bias[f0];
      float4 o;
      o.x = acc[at][bt][0] + bv.x; o.y = acc[at][bt][1] + bv.y;
      o.z = acc[at][bt][2] + bv.z; o.w = acc[at][bt][3] + bv.w;
      *(float4*)&Cf[(size_t)tkn * 768 + f0] = o;
    }
}

// ---------------- MFMA flash attention v6 (unchanged from R8) --------------------
__global__ __launch_bounds__(512, 4) void flash_attn(const bf16* __restrict__ Q,
                                                     const bf16* __restrict__ K,
                                                     const bf16* __restrict__ Vt,
                                                     bf16* __restrict__ ctx) {
  __shared__ bf16 Ks[2][4096];
  __shared__ bf16 Vs[2][4096];
  __shared__ bf16 Pt[8][16 * 72];
  const int t = threadIdx.x;
  const int w = t >> 6, lane = t & 63;
  const int mi = lane & 15, qd = lane >> 4;
  const int bh   = blockIdx.x % 24;
  const int qrev = blockIdx.x / 24;           // heavy blocks (large q0) first
  const int q0 = T_ - 128 - qrev * 128;
  const int b = bh / H_, h = bh % H_;
  const size_t bTD = (size_t)b * T_ * D_;
  const char* Kp = (const char*)(K  + bTD + (size_t)h * HD_);
  const char* Vp = (const char*)(Vt + (size_t)b * D_ * T_ + (size_t)h * HD_ * T_);
  const int qw = q0 + w * 16;                 // wave's 16 q-rows

  const int rl = t >> 3, c = (t & 7) ^ (rl & 7);
  const int vkoff = rl * 1536 + c * 16;
  const int vvoff = rl * 8192 + c * 16;

  int fidx[4][2];
  #pragma unroll
  for (int jt = 0; jt < 4; ++jt)
    #pragma unroll
    for (int kt = 0; kt < 2; ++kt)
      fidx[jt][kt] = (jt * 16 + mi) * 64 + (((kt * 4 + qd) ^ (mi & 7)) * 8);

  bf16x8 qf[2];
  const bf16* Qp = Q + bTD + (size_t)h * HD_;
  #pragma unroll
  for (int kt = 0; kt < 2; ++kt)
    qf[kt] = *(const bf16x8*)(Qp + (size_t)(qw + mi) * D_ + kt * 32 + qd * 8);

  f32x4 oacc[4] = {};
  float lst = 0.f;
  const int ntiles = q0 / 64 + 2;

  GLD16(Kp + vkoff, &Ks[0][w * 512]);
  GLD16(Vp + vvoff, &Vs[0][w * 512]);

  for (int tt = 0; tt < ntiles; ++tt) {
    __syncthreads();
    const int par = tt & 1;
    if (tt + 1 < ntiles) {
      const size_t j1 = (size_t)(tt + 1) * 64;
      const int np = par ^ 1;
      GLD16(Kp + vkoff + j1 * 1536, &Ks[np][w * 512]);
      GLD16(Vp + vvoff + j1 * 2,    &Vs[np][w * 512]);
    }
    const int j0 = tt * 64;
    if (j0 > qw + 15) continue;               // fully masked for this wave

    f32x4 sacc[4] = {};
    #pragma unroll
    for (int jt = 0; jt < 4; ++jt)
      #pragma unroll
      for (int kt = 0; kt < 2; ++kt) {
        bf16x8 kf = *(const bf16x8*)&Ks[par][fidx[jt][kt]];
        sacc[jt] = __builtin_amdgcn_mfma_f32_16x16x32_bf16(kf, qf[kt], sacc[jt], 0, 0, 0);
      }

    if (j0 + 63 > qw) {                       // causal mask, diagonal tiles only
      const int qg = qw + mi;
      #pragma unroll
      for (int jt = 0; jt < 4; ++jt)
        #pragma unroll
        for (int r = 0; r < 4; ++r) {
          int jg = j0 + jt * 16 + qd * 4 + r;
          if (jg > qg) sacc[jt][r] = -1e30f;
        }
    }

    #pragma unroll
    for (int jt = 0; jt < 4; ++jt) {
      float p0 = fexp2(sacc[jt][0]);
      float p1 = fexp2(sacc[jt][1]);
      float p2 = fexp2(sacc[jt][2]);
      float p3 = fexp2(sacc[jt][3]);
      lst += (p0 + p1) + (p2 + p3);
      union { uint32_t u[2]; uint64_t d; } pw;
      pw.u[0] = pktr(p0, p1);
      pw.u[1] = pktr(p2, p3);
      *(uint64_t*)&Pt[w][mi * 72 + jt * 16 + qd * 4] = pw.d;
    }

    asm volatile("s_waitcnt lgkmcnt(0)" ::: "memory");  // wave's P writes visible

    #pragma unroll
    for (int ktp = 0; ktp < 2; ++ktp) {
      bf16x8 pfx = *(const bf16x8*)&Pt[w][mi * 72 + ktp * 32 + qd * 8];
      #pragma unroll
      for (int dt = 0; dt < 4; ++dt) {
        bf16x8 vf = *(const bf16x8*)&Vs[par][fidx[dt][ktp]];
        oacc[dt] = __builtin_amdgcn_mfma_f32_16x16x32_bf16(vf, pfx, oacc[dt], 0, 0, 0);
      }
    }
  }

  float l = lst;
  l += __shfl_xor(l, 16);
  l += __shfl_xor(l, 32);
  float inv = __builtin_amdgcn_rcpf(l);
  const int qg = qw + mi;
  bf16* cp = ctx + bTD + (size_t)qg * D_ + h * HD_ + qd * 4;
  #pragma unroll
  for (int dt = 0; dt < 4; ++dt) {
    union { bf16 o[4]; uint2 u; } pko;
    #pragma unroll
    for (int r = 0; r < 4; ++r) pko.o[r] = __float2bfloat16(oacc[dt][r] * inv);
    *(uint2*)(cp + dt * 16) = pko.u;
  }
}

// ---------------- launch ----------------
extern "C" void kernel_launch(void* const* d_in, const int* in_sizes, int n_in,
                              void* d_out, int out_size, void* d_ws, size_t ws_size,
                              hipStream_t stream) {
  const float* x  = (const float*)d_in[0];
  const float* Wq = (const float*)d_in[1];
  const float* Wk = (const float*)d_in[2];
  const float* Wv = (const float*)d_in[3];
  const float* Wo = (const float*)d_in[4];
  const float* bo = (const float*)d_in[5];
  float* out = (float*)d_out;

  char* ws = (char*)d_ws;
  const size_t SZ  = (size_t)M_ * D_ * 2;
  const size_t WSZ = (size_t)D_ * D_ * 2;
  bf16* xb   = (bf16*)(ws);                 // [M, D]
  bf16* Qb   = (bf16*)(ws + 1 * SZ);        // [B,T,D]
  bf16* Kb   = (bf16*)(ws + 2 * SZ);        // [B,T,D], pre-scaled by SCL
  bf16* Vtg  = (bf16*)(ws + 3 * SZ);        // [B][D][T]
  bf16* ctxb = (bf16*)(ws + 4 * SZ);        // [B,T,D]
  bf16* Wqb  = (bf16*)(ws + 5 * SZ);
  bf16* Wkb  = (bf16*)(ws + 5 * SZ + 1 * WSZ);
  bf16* Wvb  = (bf16*)(ws + 5 * SZ + 2 * WSZ);
  bf16* Wob  = (bf16*)(ws + 5 * SZ + 3 * WSZ);

  cvt_all<<<6144 + 4 * 576, 256, 0, stream>>>(x, Wq, Wk, Wv, Wo, xb, Wqb, Wkb, Wvb, Wob);

  gemm_qkv<<<1152, 256, 0, stream>>>(xb, Wqb, Wkb, Wvb, Qb, Kb, Vtg);

  flash_attn<<<(T_ / 128) * B_ * H_, 512, 0, stream>>>(Qb, Kb, Vtg, ctxb);

  gemm_out<<<384, 256, 0, stream>>>(ctxb, Wob, out, bo);
}